// Round 3
// baseline (10577.653 us; speedup 1.0000x reference)
//
#include <hip/hip_runtime.h>

// SubLSTM persistent kernel for MI355X (gfx950).
// B=32, T=1024, I=H=768. 96 WGs x 256 threads; WG g owns h-columns [8g,8g+8).
// Weights (w_ih||w_hh rows for its 32 gate-rows, bf16) live in REGISTERS as
// MFMA A-fragments. Per step: stage x_t / h_t into swizzled LDS, one 32x32x16
// bf16 MFMA tile K-split over 4 waves, LDS reduce, lane-local gate update,
// write h (bf16, ws double buffer) + y (f32, d_out), software grid barrier.
// Plain launch (NOT cooperative): 96 WGs x 48KB LDS x 256 thr on 256 CUs are
// trivially co-resident, so the sense-reversal barrier is safe.

typedef __bf16 bf16x8 __attribute__((ext_vector_type(8)));
typedef float f32x16 __attribute__((ext_vector_type(16)));

#define NB 32
#define NT 1024
#define NI 768
#define NH 768
#define HC 8
#define NWG 96

union BU { bf16x8 v; uint4 u; };

__device__ __forceinline__ bf16x8 pack8(float4 a, float4 b) {
  bf16x8 v;
  v[0] = (__bf16)a.x; v[1] = (__bf16)a.y; v[2] = (__bf16)a.z; v[3] = (__bf16)a.w;
  v[4] = (__bf16)b.x; v[5] = (__bf16)b.y; v[6] = (__bf16)b.z; v[7] = (__bf16)b.w;
  return v;
}

__device__ __forceinline__ uint4 as_u4(bf16x8 v) { BU r; r.v = v; return r.u; }

__device__ __forceinline__ float sigf(float v) {
  return 1.0f / (1.0f + __expf(-v));
}

// Device-scope sense-style grid barrier: relaxed spin + explicit agent fences.
__device__ __forceinline__ void grid_barrier(unsigned* cnt, unsigned* gen) {
  __syncthreads();
  if (threadIdx.x == 0) {
    __builtin_amdgcn_fence(__ATOMIC_RELEASE, "agent");  // publish h writes
    unsigned g0 = __hip_atomic_load(gen, __ATOMIC_RELAXED, __HIP_MEMORY_SCOPE_AGENT);
    unsigned a = __hip_atomic_fetch_add(cnt, 1u, __ATOMIC_ACQ_REL, __HIP_MEMORY_SCOPE_AGENT);
    if (a == (unsigned)(NWG - 1)) {
      __hip_atomic_store(cnt, 0u, __ATOMIC_RELAXED, __HIP_MEMORY_SCOPE_AGENT);
      __hip_atomic_fetch_add(gen, 1u, __ATOMIC_RELEASE, __HIP_MEMORY_SCOPE_AGENT);
    } else {
      while (__hip_atomic_load(gen, __ATOMIC_RELAXED, __HIP_MEMORY_SCOPE_AGENT) == g0) {
        __builtin_amdgcn_s_sleep(1);
      }
    }
    __builtin_amdgcn_fence(__ATOMIC_ACQUIRE, "agent");  // see others' h writes
  }
  __syncthreads();
}

extern "C" __global__ __launch_bounds__(256, 1)
void sublstm_pers(const float* __restrict__ x,
                  const float* __restrict__ w_ih,
                  const float* __restrict__ w_hh,
                  const float* __restrict__ b_ih,
                  const float* __restrict__ b_hh,
                  float* __restrict__ out,
                  unsigned short* __restrict__ hb,   // 2 x [32][768] bf16 in ws
                  unsigned* __restrict__ bar)        // {cnt, gen} in ws
{
  __shared__ uint4 smem[3072];  // 48KB: [32][768] bf16 K-chunk, XOR-swizzled; reused for reduction
  const int tid = threadIdx.x;
  const int wv  = tid >> 6;     // wave 0..3 (owns K range [192*wv, 192*wv+192) per chunk)
  const int ln  = tid & 63;
  const int c0  = blockIdx.x * HC;

  // Barrier counters arrive 0xAA-poisoned; exactly-once init via CAS from poison.
  if (tid == 0) {
    unsigned e0 = 0xAAAAAAAAu;
    __hip_atomic_compare_exchange_strong(&bar[0], &e0, 0u, __ATOMIC_RELAXED,
                                         __ATOMIC_RELAXED, __HIP_MEMORY_SCOPE_AGENT);
    unsigned e1 = 0xAAAAAAAAu;
    __hip_atomic_compare_exchange_strong(&bar[1], &e1, 0u, __ATOMIC_RELAXED,
                                         __ATOMIC_RELAXED, __HIP_MEMORY_SCOPE_AGENT);
  }

  // ---- A-fragments (weights) -> registers, loaded once ----
  // A rows r = 4*colidx + gate (interleaved). Lane l holds A[l&31][8*(l>>5)+j].
  bf16x8 afx[12], afh[12];
  {
    const int r   = ln & 31;
    const int g   = r & 3;                 // 0:i 1:f 2:z 3:o
    const int col = c0 + (r >> 2);
    const int khi = 8 * (ln >> 5);
    const float* rowx = w_ih + (size_t)(g * NH + col) * NI;
    const float* rowh = w_hh + (size_t)(g * NH + col) * NH;
#pragma unroll
    for (int kk = 0; kk < 12; ++kk) {
      const int kg = 192 * wv + 16 * kk + khi;
      const float4* p0 = (const float4*)(rowx + kg);
      afx[kk] = pack8(p0[0], p0[1]);
      const float4* p1 = (const float4*)(rowh + kg);
      afh[kk] = pack8(p1[0], p1[1]);
    }
  }

  // Cell ownership: wave wv, lane ln -> (batch = ln&31, col = c0 + 2*wv + (ln>>5)),
  // gates in D regs [4*wv .. 4*wv+3] (i,f,z,o).
  const int myb   = ln & 31;
  const int mycol = c0 + 2 * wv + (ln >> 5);
  const float bi0 = b_ih[0 * NH + mycol] + b_hh[0 * NH + mycol];
  const float bi1 = b_ih[1 * NH + mycol] + b_hh[1 * NH + mycol];
  const float bi2 = b_ih[2 * NH + mycol] + b_hh[2 * NH + mycol];
  const float bi3 = b_ih[3 * NH + mycol] + b_hh[3 * NH + mycol];
  float cstate = 0.0f;

  const int sb = tid >> 3;  // staging: batch row 0..31
  const int ss = tid & 7;   // staging: 8 threads per row

  // Prologue: stage x_0 (f32 -> bf16, swizzled LDS).
#pragma unroll
  for (int j = 0; j < 12; ++j) {
    const int k0 = ss * 8 + 64 * j;
    const float4* px = (const float4*)(x + (size_t)sb * (NT * NI) + k0);
    const int byte = (sb * 1536 + k0 * 2) ^ ((sb & 7) << 4);
    smem[byte >> 4] = as_u4(pack8(px[0], px[1]));
  }

  int cur = 0;
#pragma unroll 1
  for (int t = 0; t < NT; ++t) {
    __syncthreads();
    f32x16 acc = {0,0,0,0,0,0,0,0,0,0,0,0,0,0,0,0};

    // ---- chunk 0: x_t part (w_ih) ----
#pragma unroll
    for (int kk = 0; kk < 12; ++kk) {
      const int kl = 192 * wv + 16 * kk + 8 * (ln >> 5);
      const int byte = ((ln & 31) * 1536 + kl * 2) ^ ((ln & 7) << 4);
      BU bfr; bfr.u = smem[byte >> 4];
      acc = __builtin_amdgcn_mfma_f32_32x32x16_bf16(afx[kk], bfr.v, acc, 0, 0, 0);
    }
    __syncthreads();

    // ---- stage h_t (bf16 copy; zeros at t==0 so hb needs no pre-zeroing) ----
#pragma unroll
    for (int j = 0; j < 12; ++j) {
      const int k0 = ss * 8 + 64 * j;
      uint4 v = make_uint4(0u, 0u, 0u, 0u);
      if (t > 0) v = *(const uint4*)(hb + (size_t)cur * (NB * NH) + sb * NH + k0);
      const int byte = (sb * 1536 + k0 * 2) ^ ((sb & 7) << 4);
      smem[byte >> 4] = v;
    }
    __syncthreads();

    // ---- chunk 1: h_t part (w_hh) ----
#pragma unroll
    for (int kk = 0; kk < 12; ++kk) {
      const int kl = 192 * wv + 16 * kk + 8 * (ln >> 5);
      const int byte = ((ln & 31) * 1536 + kl * 2) ^ ((ln & 7) << 4);
      BU bfr; bfr.u = smem[byte >> 4];
      acc = __builtin_amdgcn_mfma_f32_32x32x16_bf16(afh[kk], bfr.v, acc, 0, 0, 0);
    }
    __syncthreads();

    // ---- K-reduction across waves via LDS (overlay on smem) ----
    {
      float* red = (float*)smem;
      float4* dst = (float4*)(red + (wv * 64 + ln) * 16);
      dst[0] = make_float4(acc[0],  acc[1],  acc[2],  acc[3]);
      dst[1] = make_float4(acc[4],  acc[5],  acc[6],  acc[7]);
      dst[2] = make_float4(acc[8],  acc[9],  acc[10], acc[11]);
      dst[3] = make_float4(acc[12], acc[13], acc[14], acc[15]);
    }
    __syncthreads();
    {
      const float* red = (const float*)smem;
      float s0 = bi0, s1 = bi1, s2 = bi2, s3 = bi3;
#pragma unroll
      for (int w2 = 0; w2 < 4; ++w2) {
        const float4 p = *(const float4*)(red + ((w2 * 64 + ln) * 16 + 4 * wv));
        s0 += p.x; s1 += p.y; s2 += p.z; s3 += p.w;
      }
      const float gi = sigf(s0), gf = sigf(s1), gz = sigf(s2), go = sigf(s3);
      cstate = gf * cstate + (gz - gi);
      const float hval = sigf(cstate) - go;
      union { __bf16 b; unsigned short u; } cv;
      cv.b = (__bf16)hval;
      hb[(size_t)(cur ^ 1) * (NB * NH) + myb * NH + mycol] = cv.u;
      out[((size_t)myb * NT + t) * NH + mycol] = hval;
    }

    if (t < NT - 1) {
      __syncthreads();
      // Stage x_{t+1} BEFORE the barrier: hides global-x latency under the wait.
#pragma unroll
      for (int j = 0; j < 12; ++j) {
        const int k0 = ss * 8 + 64 * j;
        const float4* px = (const float4*)(x + (size_t)sb * (NT * NI) + (size_t)(t + 1) * NI + k0);
        const int byte = (sb * 1536 + k0 * 2) ^ ((sb & 7) << 4);
        smem[byte >> 4] = as_u4(pack8(px[0], px[1]));
      }
      grid_barrier(&bar[0], &bar[1]);
    }
    cur ^= 1;
  }
}

extern "C" void kernel_launch(void* const* d_in, const int* in_sizes, int n_in,
                              void* d_out, int out_size, void* d_ws, size_t ws_size,
                              hipStream_t stream) {
  const float* x    = (const float*)d_in[0];
  const float* w_ih = (const float*)d_in[1];
  const float* w_hh = (const float*)d_in[2];
  const float* b_ih = (const float*)d_in[3];
  const float* b_hh = (const float*)d_in[4];
  float* out = (float*)d_out;

  unsigned short* hb = (unsigned short*)d_ws;                       // 2*32*768 bf16 = 96KB
  unsigned* bar = (unsigned*)((char*)d_ws + 2 * NB * NH * sizeof(unsigned short));

  sublstm_pers<<<dim3(NWG), dim3(256), 0, stream>>>(x, w_ih, w_hh, b_ih, b_hh,
                                                    out, hb, bar);
}

// Round 4
// 5316.772 us; speedup vs baseline: 1.9895x; 1.9895x over previous
//
#include <hip/hip_runtime.h>

// SubLSTM persistent kernel for MI355X (gfx950).  Round 4.
// B=32, T=1024, I=H=768. 96 WGs x 256 threads; WG g owns h-columns [8g,8g+8).
// Weights live in registers as MFMA A-fragments (bf16). Per step: one 32x32
// output tile, K=1536 split over 4 waves, 32x32x16 bf16 MFMA, swizzled-LDS
// staging, XOR-swizzled LDS K-reduction, lane-local gate update.
//
// Cross-WG h exchange uses AGENT-scope relaxed atomics (sc1 path, coherent at
// the Infinity Cache) -- NO agent fences, so no per-step buffer_wbl2 /
// buffer_inv L2 flushes (round-3 profile showed those dominating: 10.3us/step
// at 1% HBM, 1.2% MFMA). Barrier is slot-based: WG g stores t+1 to slots[g]
// (own line, no RMW contention); WG0 polls all 96 slots then publishes gen.
// 0xAA ws poison != any target value, so no initialization is needed.

typedef __bf16 bf16x8 __attribute__((ext_vector_type(8)));
typedef float f32x16 __attribute__((ext_vector_type(16)));

#define NB 32
#define NT 1024
#define NI 768
#define NH 768
#define HC 8
#define NWG 96

union BU { bf16x8 v; uint4 u; };

__device__ __forceinline__ bf16x8 pack8(float4 a, float4 b) {
  bf16x8 v;
  v[0] = (__bf16)a.x; v[1] = (__bf16)a.y; v[2] = (__bf16)a.z; v[3] = (__bf16)a.w;
  v[4] = (__bf16)b.x; v[5] = (__bf16)b.y; v[6] = (__bf16)b.z; v[7] = (__bf16)b.w;
  return v;
}

__device__ __forceinline__ uint4 as_u4(bf16x8 v) { BU r; r.v = v; return r.u; }

__device__ __forceinline__ float sigf(float v) {
  return 1.0f / (1.0f + __expf(-v));
}

__device__ __forceinline__ unsigned ld_agent_u32(const unsigned* p) {
  return __hip_atomic_load((unsigned*)p, __ATOMIC_RELAXED, __HIP_MEMORY_SCOPE_AGENT);
}
__device__ __forceinline__ unsigned long long ld_agent_u64(const unsigned long long* p) {
  return __hip_atomic_load((unsigned long long*)p, __ATOMIC_RELAXED, __HIP_MEMORY_SCOPE_AGENT);
}

extern "C" __global__ __launch_bounds__(256, 1)
void sublstm_pers(const float* __restrict__ x,
                  const float* __restrict__ w_ih,
                  const float* __restrict__ w_hh,
                  const float* __restrict__ b_ih,
                  const float* __restrict__ b_hh,
                  float* __restrict__ out,
                  unsigned short* __restrict__ hb,   // 2 x [32][768] bf16 in ws
                  unsigned* __restrict__ slots,      // [96] arrival slots in ws
                  unsigned* __restrict__ gen)        // release word in ws
{
  __shared__ uint4 smem[3072];  // 48KB staging buffer (x_t / h_t / reduction)
  const int tid = threadIdx.x;
  const int wv  = tid >> 6;     // wave 0..3: owns K range [192*wv, 192*wv+192)
  const int ln  = tid & 63;
  const int c0  = blockIdx.x * HC;

  // ---- A-fragments (weights) -> registers, loaded once ----
  bf16x8 afx[12], afh[12];
  {
    const int r   = ln & 31;
    const int g   = r & 3;                 // 0:i 1:f 2:z 3:o
    const int col = c0 + (r >> 2);
    const int khi = 8 * (ln >> 5);
    const float* rowx = w_ih + (size_t)(g * NH + col) * NI;
    const float* rowh = w_hh + (size_t)(g * NH + col) * NH;
#pragma unroll
    for (int kk = 0; kk < 12; ++kk) {
      const int kg = 192 * wv + 16 * kk + khi;
      const float4* p0 = (const float4*)(rowx + kg);
      afx[kk] = pack8(p0[0], p0[1]);
      const float4* p1 = (const float4*)(rowh + kg);
      afh[kk] = pack8(p1[0], p1[1]);
    }
  }

  // Cell ownership: (batch = ln&31, col = c0 + 2*wv + (ln>>5)), D regs 4wv..4wv+3.
  const int myb   = ln & 31;
  const int mycol = c0 + 2 * wv + (ln >> 5);
  const float bi0 = b_ih[0 * NH + mycol] + b_hh[0 * NH + mycol];
  const float bi1 = b_ih[1 * NH + mycol] + b_hh[1 * NH + mycol];
  const float bi2 = b_ih[2 * NH + mycol] + b_hh[2 * NH + mycol];
  const float bi3 = b_ih[3 * NH + mycol] + b_hh[3 * NH + mycol];
  float cstate = 0.0f;

  const int sb = tid >> 3;  // staging: batch row 0..31
  const int ss = tid & 7;   // staging: 8 threads per row

  // Prologue: stage x_0 (f32 -> bf16, swizzled LDS).
#pragma unroll
  for (int j = 0; j < 12; ++j) {
    const int k0 = ss * 8 + 64 * j;
    const float4* px = (const float4*)(x + (size_t)sb * (NT * NI) + k0);
    const int byte = (sb * 1536 + k0 * 2) ^ ((sb & 7) << 4);
    smem[byte >> 4] = as_u4(pack8(px[0], px[1]));
  }

  int cur = 0;
#pragma unroll 1
  for (int t = 0; t < NT; ++t) {
    __syncthreads();  // staging ds_writes (prologue or pre-barrier) -> reads

    // ---- issue h_t loads early (agent-scope sc1: coherent via IF, no L2) ----
    unsigned long long ha[12], hc[12];
    if (t > 0) {
      const unsigned long long* hrow =
          (const unsigned long long*)(hb + (size_t)cur * (NB * NH) + sb * NH);
#pragma unroll
      for (int j = 0; j < 12; ++j) {
        const int k0 = ss * 8 + 64 * j;
        ha[j] = ld_agent_u64(hrow + (k0 >> 2));
        hc[j] = ld_agent_u64(hrow + (k0 >> 2) + 1);
      }
    } else {
#pragma unroll
      for (int j = 0; j < 12; ++j) { ha[j] = 0ull; hc[j] = 0ull; }
    }

    f32x16 acc = {0,0,0,0,0,0,0,0,0,0,0,0,0,0,0,0};

    // ---- chunk 0: x_t part (w_ih), h loads in flight underneath ----
#pragma unroll
    for (int kk = 0; kk < 12; ++kk) {
      const int kl = 192 * wv + 16 * kk + 8 * (ln >> 5);
      const int byte = ((ln & 31) * 1536 + kl * 2) ^ ((ln & 7) << 4);
      BU bfr; bfr.u = smem[byte >> 4];
      acc = __builtin_amdgcn_mfma_f32_32x32x16_bf16(afx[kk], bfr.v, acc, 0, 0, 0);
    }
    __syncthreads();

    // ---- write h_t to swizzled LDS ----
#pragma unroll
    for (int j = 0; j < 12; ++j) {
      const int k0 = ss * 8 + 64 * j;
      const int byte = (sb * 1536 + k0 * 2) ^ ((sb & 7) << 4);
      uint4 v;
      v.x = (unsigned)ha[j]; v.y = (unsigned)(ha[j] >> 32);
      v.z = (unsigned)hc[j]; v.w = (unsigned)(hc[j] >> 32);
      smem[byte >> 4] = v;
    }
    __syncthreads();

    // ---- chunk 1: h_t part (w_hh) ----
#pragma unroll
    for (int kk = 0; kk < 12; ++kk) {
      const int kl = 192 * wv + 16 * kk + 8 * (ln >> 5);
      const int byte = ((ln & 31) * 1536 + kl * 2) ^ ((ln & 7) << 4);
      BU bfr; bfr.u = smem[byte >> 4];
      acc = __builtin_amdgcn_mfma_f32_32x32x16_bf16(afh[kk], bfr.v, acc, 0, 0, 0);
    }
    __syncthreads();

    // ---- K-reduction across waves via LDS, XOR-swizzled (conflict-free) ----
    {
      char* base = (char*)smem;
      const int row = wv * 64 + ln;
      const int key = (row & 7) << 4;
#pragma unroll
      for (int q = 0; q < 4; ++q) {
        const int byte = (row * 64 + q * 16) ^ key;
        *(float4*)(base + byte) =
            make_float4(acc[4*q], acc[4*q+1], acc[4*q+2], acc[4*q+3]);
      }
    }
    __syncthreads();
    {
      const char* base = (const char*)smem;
      float s0 = bi0, s1 = bi1, s2 = bi2, s3 = bi3;
#pragma unroll
      for (int w2 = 0; w2 < 4; ++w2) {
        const int row = w2 * 64 + ln;
        const int byte = (row * 64 + wv * 16) ^ ((row & 7) << 4);
        const float4 p = *(const float4*)(base + byte);
        s0 += p.x; s1 += p.y; s2 += p.z; s3 += p.w;
      }
      const float gi = sigf(s0), gf = sigf(s1), gz = sigf(s2), go = sigf(s3);
      cstate = gf * cstate + (gz - gi);
      const float hval = sigf(cstate) - go;
      union { __bf16 b; unsigned short u; } cv;
      cv.b = (__bf16)hval;
      // agent-scope store: device-coherent via IF, no fence needed
      __hip_atomic_store(&hb[(size_t)(cur ^ 1) * (NB * NH) + myb * NH + mycol],
                         cv.u, __ATOMIC_RELAXED, __HIP_MEMORY_SCOPE_AGENT);
      out[((size_t)myb * NT + t) * NH + mycol] = hval;
    }

    if (t < NT - 1) {
      // Per-wave drain: h stores are at the coherence point before arrival.
      asm volatile("s_waitcnt vmcnt(0)" ::: "memory");
      __syncthreads();  // all 4 waves drained; reduction reads done

      const unsigned tgt = (unsigned)(t + 1);
      if (tid == 0)
        __hip_atomic_store(&slots[blockIdx.x], tgt, __ATOMIC_RELAXED,
                           __HIP_MEMORY_SCOPE_AGENT);

      // Stage x_{t+1} while the barrier settles (loads fly during the spin).
#pragma unroll
      for (int j = 0; j < 12; ++j) {
        const int k0 = ss * 8 + 64 * j;
        const float4* px = (const float4*)(x + (size_t)sb * (NT * NI) +
                                           (size_t)(t + 1) * NI + k0);
        const int byte = (sb * 1536 + k0 * 2) ^ ((sb & 7) << 4);
        smem[byte >> 4] = as_u4(pack8(px[0], px[1]));
      }

      if (blockIdx.x == 0) {
        if (tid < NWG) {
          while (ld_agent_u32(&slots[tid]) != tgt) __builtin_amdgcn_s_sleep(1);
        }
        __syncthreads();                    // all slots observed
        if (tid == 0)
          __hip_atomic_store(gen, tgt, __ATOMIC_RELAXED, __HIP_MEMORY_SCOPE_AGENT);
      } else {
        if (tid == 0) {
          while (ld_agent_u32(gen) != tgt) __builtin_amdgcn_s_sleep(1);
        }
        // loop-top __syncthreads releases the other threads of this WG
      }
    }
    cur ^= 1;
  }
}

extern "C" void kernel_launch(void* const* d_in, const int* in_sizes, int n_in,
                              void* d_out, int out_size, void* d_ws, size_t ws_size,
                              hipStream_t stream) {
  const float* x    = (const float*)d_in[0];
  const float* w_ih = (const float*)d_in[1];
  const float* w_hh = (const float*)d_in[2];
  const float* b_ih = (const float*)d_in[3];
  const float* b_hh = (const float*)d_in[4];
  float* out = (float*)d_out;

  unsigned short* hb = (unsigned short*)d_ws;               // 2*32*768*2B = 96KB
  char* wsb = (char*)d_ws + 2 * NB * NH * sizeof(unsigned short);
  unsigned* slots = (unsigned*)wsb;                          // 96 * 4B
  unsigned* gen   = (unsigned*)(wsb + 512);                  // separate line

  sublstm_pers<<<dim3(NWG), dim3(256), 0, stream>>>(x, w_ih, w_hh, b_ih, b_hh,
                                                    out, hb, slots, gen);
}